// Round 4
// baseline (511.150 us; speedup 1.0000x reference)
//
#include <hip/hip_runtime.h>
#include <cstdint>
#include <cstddef>

// ---------------------------------------------------------------------------
// 2-layer GCN, round 4 (round-3 design + hb32 allocation fix).
//   memset(cursor,ovf_cnt)
//   k_part : partition packed (src,dst) u16x2 edges into 391 dst-buckets
//            (128 nodes each) with LDS regroup -> near-coalesced writes
//   k_fill2: per-bucket ELL build in LDS (32KB slab), coalesced copy-out,
//            emits cnt + dinv
//   k_gemm<256>: hb1 = bf16((x@W1)*dinv[row]) into 4 channel-chunk slabs
//   k_agg  : chunked gather (L2-resident 3.2MB slab per chunk) + bias + ReLU
//   k_gemm<128>, k_agg again.
// ---------------------------------------------------------------------------

#define ELL_STRIDE 128
#define BCAP 8192      // per-bucket edge capacity (avg 4092, +64 sigma safe)
#define OVF_CAP 1024
#define PART_T 4096    // edges per k_part block

__device__ __forceinline__ unsigned short f2bf(float f) {
  unsigned int u = __float_as_uint(f);
  unsigned int r = (u + 0x7fffu + ((u >> 16) & 1u)) >> 16;   // RNE
  return (unsigned short)r;
}
__device__ __forceinline__ float2 bfpair(unsigned int p) {
  float2 r;
  r.x = __uint_as_float(p << 16);
  r.y = __uint_as_float(p & 0xffff0000u);
  return r;
}

// ---------------- phase 1: bucket partition ----------------
__global__ __launch_bounds__(256) void k_part(const int* __restrict__ src,
                                              const int* __restrict__ dst,
                                              int* __restrict__ cursor,
                                              unsigned int* __restrict__ part,
                                              int* __restrict__ ovf_cnt,
                                              int* __restrict__ ovf,
                                              int E, int NB) {
  __shared__ unsigned int stage1[PART_T];
  __shared__ unsigned int stage2[PART_T];
  __shared__ int hist[512];
  __shared__ int base_g[512];
  __shared__ int base_l[512];
  __shared__ int cl[512];
  const int tid = threadIdx.x;
  const int e0 = blockIdx.x * PART_T;
  int valid = E - e0; if (valid > PART_T) valid = PART_T;

  for (int b = tid; b < NB; b += 256) { hist[b] = 0; cl[b] = 0; }
  __syncthreads();
  for (int i = tid; i < valid; i += 256) {
    int e = e0 + i;
    unsigned int v = (unsigned int)(src[e] & 0xffff) | ((unsigned int)dst[e] << 16);
    stage1[i] = v;
    atomicAdd(&hist[(v >> 16) >> 7], 1);
  }
  __syncthreads();
  for (int b = tid; b < NB; b += 256) base_g[b] = atomicAdd(&cursor[b], hist[b]);
  if (tid == 0) {
    int run = 0;
    for (int b = 0; b < NB; ++b) { base_l[b] = run; run += hist[b]; }
  }
  __syncthreads();
  for (int i = tid; i < valid; i += 256) {
    unsigned int v = stage1[i];
    int b = (v >> 16) >> 7;
    int pos = base_l[b] + atomicAdd(&cl[b], 1);
    stage2[pos] = v;
  }
  __syncthreads();
  // copy out: consecutive i within a bucket run -> consecutive global addrs
  for (int i = tid; i < valid; i += 256) {
    unsigned int v = stage2[i];
    int b = (v >> 16) >> 7;
    int g = base_g[b] + (i - base_l[b]);
    if (g < BCAP) {
      part[(size_t)b * BCAP + g] = v;
    } else {
      int p = atomicAdd(ovf_cnt, 1);
      if (p < OVF_CAP) { ovf[2 * p] = (int)(v & 0xffffu); ovf[2 * p + 1] = (int)(v >> 16); }
    }
  }
}

// ---------------- phase 2: per-bucket ELL build in LDS ----------------
__global__ __launch_bounds__(256) void k_fill2(const unsigned int* __restrict__ part,
                                               const int* __restrict__ cursor,
                                               unsigned short* __restrict__ col,
                                               int* __restrict__ cnt,
                                               float* __restrict__ dinv,
                                               int* __restrict__ ovf_cnt,
                                               int* __restrict__ ovf, int N) {
  __shared__ unsigned short slab[128 * ELL_STRIDE];  // 32 KB
  __shared__ int cl[128];
  const int tid = threadIdx.x;
  const int b = blockIdx.x;
  if (tid < 128) cl[tid] = 0;
  __syncthreads();
  int count = cursor[b]; if (count > BCAP) count = BCAP;
  const unsigned int* p = part + (size_t)b * BCAP;
  for (int i = tid; i < count; i += 256) {
    unsigned int v = p[i];
    int row = (v >> 16) & 127;
    int k = atomicAdd(&cl[row], 1);
    if (k < ELL_STRIDE) {
      slab[row * ELL_STRIDE + k] = (unsigned short)(v & 0xffffu);
    } else {
      int q = atomicAdd(ovf_cnt, 1);
      if (q < OVF_CAP) { ovf[2 * q] = (int)(v & 0xffffu); ovf[2 * q + 1] = (int)(v >> 16); }
    }
  }
  __syncthreads();
  uint4* d4 = (uint4*)(col + (size_t)b * 128 * ELL_STRIDE);
  const uint4* s4 = (const uint4*)slab;
  #pragma unroll
  for (int i = 0; i < (128 * ELL_STRIDE * 2) / (16 * 256); ++i)
    d4[i * 256 + tid] = s4[i * 256 + tid];
  if (tid < 128) {
    int node = b * 128 + tid;
    if (node < N) {
      int c = cl[tid];
      cnt[node] = c;
      dinv[node] = rsqrtf((float)c + 1.0f);
    }
  }
}

// ---------------- fp32 GEMM -> bf16 pre-scaled, channel-chunk slab layout ---
// hb32: 4 slabs, slab c = uint[N][16] holding bf16 pairs of channels 32c..32c+31
template <int K>
__global__ __launch_bounds__(256) void k_gemm(const float* __restrict__ X,
                                              const float* __restrict__ W,
                                              const float* __restrict__ dinv,
                                              unsigned int* __restrict__ hb32,
                                              int M) {
  __shared__ float xs[32][128];
  __shared__ float ws[32][128];
  const int tid = threadIdx.x;
  const int row0 = blockIdx.x * 128;
  const int tr = (tid >> 4) * 8;
  const int tc = (tid & 15) * 8;
  float acc[8][8];
  #pragma unroll
  for (int i = 0; i < 8; ++i)
    #pragma unroll
    for (int j = 0; j < 8; ++j) acc[i][j] = 0.f;

  for (int k0 = 0; k0 < K; k0 += 32) {
    __syncthreads();
    #pragma unroll
    for (int v = 0; v < 4; ++v) {
      int idx = v * 256 + tid;
      int r = idx >> 3;
      int kk = (idx & 7) * 4;
      float4 val = make_float4(0.f, 0.f, 0.f, 0.f);
      int gr = row0 + r;
      if (gr < M) val = *(const float4*)(X + (size_t)gr * K + k0 + kk);
      xs[kk + 0][r] = val.x; xs[kk + 1][r] = val.y;
      xs[kk + 2][r] = val.z; xs[kk + 3][r] = val.w;
      int wr = idx >> 5;
      int wc = (idx & 31) * 4;
      *(float4*)&ws[wr][wc] = *(const float4*)(W + (size_t)(k0 + wr) * 128 + wc);
    }
    __syncthreads();
    #pragma unroll
    for (int kk = 0; kk < 32; ++kk) {
      float a[8], b[8];
      *(float4*)&a[0] = *(const float4*)&xs[kk][tr];
      *(float4*)&a[4] = *(const float4*)&xs[kk][tr + 4];
      *(float4*)&b[0] = *(const float4*)&ws[kk][tc];
      *(float4*)&b[4] = *(const float4*)&ws[kk][tc + 4];
      #pragma unroll
      for (int i = 0; i < 8; ++i)
        #pragma unroll
        for (int j = 0; j < 8; ++j)
          acc[i][j] += a[i] * b[j];
    }
  }
  const int chunk = tc >> 5;            // channel chunk 0..3
  const int cpo = (tc & 31) >> 1;       // uint offset within chunk row: 0,4,8,12
  #pragma unroll
  for (int i = 0; i < 8; ++i) {
    int gr = row0 + tr + i;
    if (gr < M) {
      float di = dinv[gr];
      unsigned int p0 = (unsigned int)f2bf(acc[i][0] * di) |
                        ((unsigned int)f2bf(acc[i][1] * di) << 16);
      unsigned int p1 = (unsigned int)f2bf(acc[i][2] * di) |
                        ((unsigned int)f2bf(acc[i][3] * di) << 16);
      unsigned int p2 = (unsigned int)f2bf(acc[i][4] * di) |
                        ((unsigned int)f2bf(acc[i][5] * di) << 16);
      unsigned int p3 = (unsigned int)f2bf(acc[i][6] * di) |
                        ((unsigned int)f2bf(acc[i][7] * di) << 16);
      *(uint4*)(hb32 + (size_t)chunk * M * 16 + (size_t)gr * 16 + cpo) =
          make_uint4(p0, p1, p2, p3);
    }
  }
}

// ---------------- chunked ELL aggregate + bias + ReLU ----------------
// chunk = blockIdx.x / blocks_per_chunk -> chunks run (approximately) in
// sequence, so each 3.2MB slab stays L2-resident while it's being gathered.
// wave = 1 dst node: 4 edge-slots (sub) x 16 channel-pairs (cp).
__global__ __launch_bounds__(256) void k_agg(const unsigned int* __restrict__ hb32,
                                             const int* __restrict__ cnt,
                                             const unsigned short* __restrict__ col,
                                             const float* __restrict__ dinv,
                                             const int* __restrict__ ovf_cnt,
                                             const int* __restrict__ ovf,
                                             const float* __restrict__ bias,
                                             float* __restrict__ out,
                                             int n, int blocks_per_chunk) {
  const int wave = threadIdx.x >> 6;
  const int lane = threadIdx.x & 63;
  const int chunk = blockIdx.x / blocks_per_chunk;
  const int nblk = blockIdx.x % blocks_per_chunk;
  const int d = nblk * 4 + wave;
  if (d >= n) return;
  const int sub = lane >> 4;        // edge slot 0..3
  const int cp = lane & 15;         // channel pair 0..15 (32 ch per chunk)
  const unsigned int* slab = hb32 + (size_t)chunk * n * 16;

  float2 acc = make_float2(0.f, 0.f);
  if (sub == 0) acc = bfpair(slab[(size_t)d * 16 + cp]);   // self-loop term

  int m = cnt[d]; if (m > ELL_STRIDE) m = ELL_STRIDE;
  const unsigned short* crow = col + (size_t)d * ELL_STRIDE;
  for (int k = sub; k < m; k += 4) {
    int c = crow[k];
    float2 v = bfpair(slab[(size_t)c * 16 + cp]);
    acc.x += v.x; acc.y += v.y;
  }
  if (sub == 0) {
    int V = *ovf_cnt; if (V > OVF_CAP) V = OVF_CAP;
    for (int j = 0; j < V; ++j) {
      if (ovf[2 * j + 1] == d) {
        float2 v = bfpair(slab[(size_t)ovf[2 * j] * 16 + cp]);
        acc.x += v.x; acc.y += v.y;
      }
    }
  }
  acc.x += __shfl_xor(acc.x, 16); acc.y += __shfl_xor(acc.y, 16);
  acc.x += __shfl_xor(acc.x, 32); acc.y += __shfl_xor(acc.y, 32);
  if (sub == 0) {
    float di = dinv[d];
    float2 bv = *(const float2*)(bias + chunk * 32 + cp * 2);
    float rx = di * acc.x + bv.x;
    float ry = di * acc.y + bv.y;
    rx = rx > 0.f ? rx : 0.f;
    ry = ry > 0.f ? ry : 0.f;
    *(float2*)(out + (size_t)d * 128 + chunk * 32 + cp * 2) = make_float2(rx, ry);
  }
}

// ---------------------------------------------------------------------------
extern "C" void kernel_launch(void* const* d_in, const int* in_sizes, int n_in,
                              void* d_out, int out_size, void* d_ws, size_t ws_size,
                              hipStream_t stream) {
  const float* x  = (const float*)d_in[0];
  const int*   ei = (const int*)d_in[1];
  const float* W1 = (const float*)d_in[2];
  const float* b1 = (const float*)d_in[3];
  const float* W2 = (const float*)d_in[4];
  const float* b2 = (const float*)d_in[5];
  float* out = (float*)d_out;

  const int IN_CH = 256;
  const int N = in_sizes[0] / IN_CH;   // 50000
  const int E = in_sizes[1] / 2;       // 1,600,000
  const int NB = (N + 127) >> 7;       // 391 buckets of 128 dst nodes

  const int* src = ei;
  const int* dst = ei + E;

  char* ws = (char*)d_ws;
  size_t off = 0;
  auto carve = [&](size_t bytes) {
    void* p = ws + off;
    off += (bytes + 255) & ~(size_t)255;
    return p;
  };
  int*            cursor  = (int*)carve((size_t)NB * 4);
  int*            ovf_cnt = (int*)carve(4);
  size_t zero_bytes = off;                        // cursor + ovf_cnt
  int*            ovf     = (int*)carve((size_t)OVF_CAP * 2 * 4);
  int*            cnt     = (int*)carve((size_t)N * 4);
  float*          dinv    = (float*)carve((size_t)N * 4);
  unsigned short* col     = (unsigned short*)carve((size_t)NB * 128 * ELL_STRIDE * 2);
  unsigned int*   hb32    = (unsigned int*)carve((size_t)N * 256);  // 4 chunks x N x 16 uint (N x 128 bf16)
  // union: part (dead after k_fill2) aliases aggbuf (written later by k_agg#1)
  char*           unionp  = (char*)carve((size_t)N * 128 * 4);     // 25.6MB >= part 12.8MB
  unsigned int*   part    = (unsigned int*)unionp;
  float*          aggbuf  = (float*)unionp;

  hipMemsetAsync(d_ws, 0, zero_bytes, stream);

  k_part <<<(E + PART_T - 1) / PART_T, 256, 0, stream>>>(src, dst, cursor, part,
                                                         ovf_cnt, ovf, E, NB);
  k_fill2<<<NB, 256, 0, stream>>>(part, cursor, col, cnt, dinv, ovf_cnt, ovf, N);

  int gblocks = (N + 127) / 128;
  int bpc = (N + 3) / 4;               // blocks per chunk (12500)
  k_gemm<256><<<gblocks, 256, 0, stream>>>(x, W1, dinv, hb32, N);
  k_agg<<<4 * bpc, 256, 0, stream>>>(hb32, cnt, col, dinv, ovf_cnt, ovf, b1, aggbuf,
                                     N, bpc);
  k_gemm<128><<<gblocks, 256, 0, stream>>>(aggbuf, W2, dinv, hb32, N);
  k_agg<<<4 * bpc, 256, 0, stream>>>(hb32, cnt, col, dinv, ovf_cnt, ovf, b2, out,
                                     N, bpc);
}

// Round 5
// 337.592 us; speedup vs baseline: 1.5141x; 1.5141x over previous
//
#include <hip/hip_runtime.h>
#include <cstdint>
#include <cstddef>

// ---------------------------------------------------------------------------
// 2-layer GCN, round 5.
//   memset(cursor,ovf_cnt)
//   k_part : partition packed (src,dst) u16x2 edges into 391 dst-buckets
//   k_fill2: per-bucket ELL build in LDS, coalesced copy-out, emits cnt+dinv
//   k_gemm<256>: hb1 = bf16((x@W1)*dinv[row])  row-major [N][64] uints
//   k_agg  : wave=node, lane=uint(2ch); 8-deep independent 256B row gathers
//   k_gemm<128>, k_agg again.
// ---------------------------------------------------------------------------

#define ELL_STRIDE 128
#define BCAP 8192
#define OVF_CAP 1024
#define PART_T 4096

__device__ __forceinline__ unsigned short f2bf(float f) {
  unsigned int u = __float_as_uint(f);
  unsigned int r = (u + 0x7fffu + ((u >> 16) & 1u)) >> 16;   // RNE
  return (unsigned short)r;
}
__device__ __forceinline__ float2 bfpair(unsigned int p) {
  float2 r;
  r.x = __uint_as_float(p << 16);
  r.y = __uint_as_float(p & 0xffff0000u);
  return r;
}

// ---------------- phase 1: bucket partition ----------------
__global__ __launch_bounds__(256) void k_part(const int* __restrict__ src,
                                              const int* __restrict__ dst,
                                              int* __restrict__ cursor,
                                              unsigned int* __restrict__ part,
                                              int* __restrict__ ovf_cnt,
                                              int* __restrict__ ovf,
                                              int E, int NB) {
  __shared__ unsigned int stage1[PART_T];
  __shared__ unsigned int stage2[PART_T];
  __shared__ int hist[512];
  __shared__ int base_g[512];
  __shared__ int base_l[512];
  __shared__ int cl[512];
  const int tid = threadIdx.x;
  const int e0 = blockIdx.x * PART_T;
  int valid = E - e0; if (valid > PART_T) valid = PART_T;

  for (int b = tid; b < NB; b += 256) { hist[b] = 0; cl[b] = 0; }
  __syncthreads();
  for (int i = tid; i < valid; i += 256) {
    int e = e0 + i;
    unsigned int v = (unsigned int)(src[e] & 0xffff) | ((unsigned int)dst[e] << 16);
    stage1[i] = v;
    atomicAdd(&hist[(v >> 16) >> 7], 1);
  }
  __syncthreads();
  for (int b = tid; b < NB; b += 256) base_g[b] = atomicAdd(&cursor[b], hist[b]);
  if (tid == 0) {
    int run = 0;
    for (int b = 0; b < NB; ++b) { base_l[b] = run; run += hist[b]; }
  }
  __syncthreads();
  for (int i = tid; i < valid; i += 256) {
    unsigned int v = stage1[i];
    int b = (v >> 16) >> 7;
    int pos = base_l[b] + atomicAdd(&cl[b], 1);
    stage2[pos] = v;
  }
  __syncthreads();
  for (int i = tid; i < valid; i += 256) {
    unsigned int v = stage2[i];
    int b = (v >> 16) >> 7;
    int g = base_g[b] + (i - base_l[b]);
    if (g < BCAP) {
      part[(size_t)b * BCAP + g] = v;
    } else {
      int p = atomicAdd(ovf_cnt, 1);
      if (p < OVF_CAP) { ovf[2 * p] = (int)(v & 0xffffu); ovf[2 * p + 1] = (int)(v >> 16); }
    }
  }
}

// ---------------- phase 2: per-bucket ELL build in LDS ----------------
__global__ __launch_bounds__(256) void k_fill2(const unsigned int* __restrict__ part,
                                               const int* __restrict__ cursor,
                                               unsigned short* __restrict__ col,
                                               int* __restrict__ cnt,
                                               float* __restrict__ dinv,
                                               int* __restrict__ ovf_cnt,
                                               int* __restrict__ ovf, int N) {
  __shared__ unsigned short slab[128 * ELL_STRIDE];  // 32 KB
  __shared__ int cl[128];
  const int tid = threadIdx.x;
  const int b = blockIdx.x;
  if (tid < 128) cl[tid] = 0;
  __syncthreads();
  int count = cursor[b]; if (count > BCAP) count = BCAP;
  const unsigned int* p = part + (size_t)b * BCAP;
  for (int i = tid; i < count; i += 256) {
    unsigned int v = p[i];
    int row = (v >> 16) & 127;
    int k = atomicAdd(&cl[row], 1);
    if (k < ELL_STRIDE) {
      slab[row * ELL_STRIDE + k] = (unsigned short)(v & 0xffffu);
    } else {
      int q = atomicAdd(ovf_cnt, 1);
      if (q < OVF_CAP) { ovf[2 * q] = (int)(v & 0xffffu); ovf[2 * q + 1] = (int)(v >> 16); }
    }
  }
  __syncthreads();
  uint4* d4 = (uint4*)(col + (size_t)b * 128 * ELL_STRIDE);
  const uint4* s4 = (const uint4*)slab;
  #pragma unroll
  for (int i = 0; i < (128 * ELL_STRIDE * 2) / (16 * 256); ++i)
    d4[i * 256 + tid] = s4[i * 256 + tid];
  if (tid < 128) {
    int node = b * 128 + tid;
    if (node < N) {
      int c = cl[tid];
      cnt[node] = c;
      dinv[node] = rsqrtf((float)c + 1.0f);
    }
  }
}

// ---------------- fp32 GEMM -> bf16 pre-scaled, row-major [M][64] uints ----
template <int K>
__global__ __launch_bounds__(256) void k_gemm(const float* __restrict__ X,
                                              const float* __restrict__ W,
                                              const float* __restrict__ dinv,
                                              unsigned int* __restrict__ hb,
                                              int M) {
  __shared__ float xs[32][128];
  __shared__ float ws[32][128];
  const int tid = threadIdx.x;
  const int row0 = blockIdx.x * 128;
  const int tr = (tid >> 4) * 8;
  const int tc = (tid & 15) * 8;
  float acc[8][8];
  #pragma unroll
  for (int i = 0; i < 8; ++i)
    #pragma unroll
    for (int j = 0; j < 8; ++j) acc[i][j] = 0.f;

  for (int k0 = 0; k0 < K; k0 += 32) {
    __syncthreads();
    #pragma unroll
    for (int v = 0; v < 4; ++v) {
      int idx = v * 256 + tid;
      int r = idx >> 3;
      int kk = (idx & 7) * 4;
      float4 val = make_float4(0.f, 0.f, 0.f, 0.f);
      int gr = row0 + r;
      if (gr < M) val = *(const float4*)(X + (size_t)gr * K + k0 + kk);
      xs[kk + 0][r] = val.x; xs[kk + 1][r] = val.y;
      xs[kk + 2][r] = val.z; xs[kk + 3][r] = val.w;
      int wr = idx >> 5;
      int wc = (idx & 31) * 4;
      *(float4*)&ws[wr][wc] = *(const float4*)(W + (size_t)(k0 + wr) * 128 + wc);
    }
    __syncthreads();
    #pragma unroll
    for (int kk = 0; kk < 32; ++kk) {
      float a[8], b[8];
      *(float4*)&a[0] = *(const float4*)&xs[kk][tr];
      *(float4*)&a[4] = *(const float4*)&xs[kk][tr + 4];
      *(float4*)&b[0] = *(const float4*)&ws[kk][tc];
      *(float4*)&b[4] = *(const float4*)&ws[kk][tc + 4];
      #pragma unroll
      for (int i = 0; i < 8; ++i)
        #pragma unroll
        for (int j = 0; j < 8; ++j)
          acc[i][j] += a[i] * b[j];
    }
  }
  #pragma unroll
  for (int i = 0; i < 8; ++i) {
    int gr = row0 + tr + i;
    if (gr < M) {
      float di = dinv[gr];
      unsigned int p0 = (unsigned int)f2bf(acc[i][0] * di) |
                        ((unsigned int)f2bf(acc[i][1] * di) << 16);
      unsigned int p1 = (unsigned int)f2bf(acc[i][2] * di) |
                        ((unsigned int)f2bf(acc[i][3] * di) << 16);
      unsigned int p2 = (unsigned int)f2bf(acc[i][4] * di) |
                        ((unsigned int)f2bf(acc[i][5] * di) << 16);
      unsigned int p3 = (unsigned int)f2bf(acc[i][6] * di) |
                        ((unsigned int)f2bf(acc[i][7] * di) << 16);
      *(uint4*)(hb + (size_t)gr * 64 + (tc >> 1)) = make_uint4(p0, p1, p2, p3);
    }
  }
}

// ---------------- ELL gather-aggregate + bias + ReLU ----------------
// wave = 1 dst node; lane = uint index (2 channels) of the 256B bf16 row.
// 8-deep unrolled edge loop -> 8 independent full-row gathers in flight.
__global__ __launch_bounds__(256) void k_agg(const unsigned int* __restrict__ hb,
                                             const int* __restrict__ cnt,
                                             const unsigned short* __restrict__ col,
                                             const float* __restrict__ dinv,
                                             const int* __restrict__ ovf_cnt,
                                             const int* __restrict__ ovf,
                                             const float* __restrict__ bias,
                                             float* __restrict__ out, int n) {
  const int wave = threadIdx.x >> 6;
  const int lane = threadIdx.x & 63;
  const int d = blockIdx.x * 4 + wave;
  if (d >= n) return;

  // self-loop term: hb pre-scaled by dinv, so hb[d]*dinv[d] = h[d]*dinv^2
  float2 acc = bfpair(hb[(size_t)d * 64 + lane]);

  int m = cnt[d]; if (m > ELL_STRIDE) m = ELL_STRIDE;
  const unsigned short* crow = col + (size_t)d * ELL_STRIDE;
  int k = 0;
  for (; k + 8 <= m; k += 8) {
    ushort4 ca = *(const ushort4*)(crow + k);
    ushort4 cb = *(const ushort4*)(crow + k + 4);
    unsigned int p0 = hb[(size_t)ca.x * 64 + lane];
    unsigned int p1 = hb[(size_t)ca.y * 64 + lane];
    unsigned int p2 = hb[(size_t)ca.z * 64 + lane];
    unsigned int p3 = hb[(size_t)ca.w * 64 + lane];
    unsigned int p4 = hb[(size_t)cb.x * 64 + lane];
    unsigned int p5 = hb[(size_t)cb.y * 64 + lane];
    unsigned int p6 = hb[(size_t)cb.z * 64 + lane];
    unsigned int p7 = hb[(size_t)cb.w * 64 + lane];
    float2 v0 = bfpair(p0), v1 = bfpair(p1), v2 = bfpair(p2), v3 = bfpair(p3);
    float2 v4 = bfpair(p4), v5 = bfpair(p5), v6 = bfpair(p6), v7 = bfpair(p7);
    acc.x += v0.x + v1.x + v2.x + v3.x;
    acc.y += v0.y + v1.y + v2.y + v3.y;
    acc.x += v4.x + v5.x + v6.x + v7.x;
    acc.y += v4.y + v5.y + v6.y + v7.y;
  }
  for (; k < m; ++k) {
    int c = crow[k];
    float2 v = bfpair(hb[(size_t)c * 64 + lane]);
    acc.x += v.x; acc.y += v.y;
  }
  int V = *ovf_cnt; if (V > OVF_CAP) V = OVF_CAP;
  for (int j = 0; j < V; ++j) {
    if (ovf[2 * j + 1] == d) {
      float2 v = bfpair(hb[(size_t)ovf[2 * j] * 64 + lane]);
      acc.x += v.x; acc.y += v.y;
    }
  }
  float di = dinv[d];
  float2 bv = *(const float2*)(bias + lane * 2);
  float rx = di * acc.x + bv.x;
  float ry = di * acc.y + bv.y;
  rx = rx > 0.f ? rx : 0.f;
  ry = ry > 0.f ? ry : 0.f;
  *(float2*)(out + (size_t)d * 128 + lane * 2) = make_float2(rx, ry);
}

// ---------------------------------------------------------------------------
extern "C" void kernel_launch(void* const* d_in, const int* in_sizes, int n_in,
                              void* d_out, int out_size, void* d_ws, size_t ws_size,
                              hipStream_t stream) {
  const float* x  = (const float*)d_in[0];
  const int*   ei = (const int*)d_in[1];
  const float* W1 = (const float*)d_in[2];
  const float* b1 = (const float*)d_in[3];
  const float* W2 = (const float*)d_in[4];
  const float* b2 = (const float*)d_in[5];
  float* out = (float*)d_out;

  const int IN_CH = 256;
  const int N = in_sizes[0] / IN_CH;   // 50000
  const int E = in_sizes[1] / 2;       // 1,600,000
  const int NB = (N + 127) >> 7;       // 391 buckets

  const int* src = ei;
  const int* dst = ei + E;

  char* ws = (char*)d_ws;
  size_t off = 0;
  auto carve = [&](size_t bytes) {
    void* p = ws + off;
    off += (bytes + 255) & ~(size_t)255;
    return p;
  };
  int*            cursor  = (int*)carve((size_t)NB * 4);
  int*            ovf_cnt = (int*)carve(4);
  size_t zero_bytes = off;                        // cursor + ovf_cnt
  int*            ovf     = (int*)carve((size_t)OVF_CAP * 2 * 4);
  int*            cnt     = (int*)carve((size_t)N * 4);
  float*          dinv    = (float*)carve((size_t)N * 4);
  unsigned short* col     = (unsigned short*)carve((size_t)NB * 128 * ELL_STRIDE * 2);
  unsigned int*   hb      = (unsigned int*)carve((size_t)N * 256);  // [N][64] uints
  // union: part (dead after k_fill2) aliases aggbuf (written later by k_agg#1)
  char*           unionp  = (char*)carve((size_t)N * 128 * 4);
  unsigned int*   part    = (unsigned int*)unionp;
  float*          aggbuf  = (float*)unionp;

  hipMemsetAsync(d_ws, 0, zero_bytes, stream);

  k_part <<<(E + PART_T - 1) / PART_T, 256, 0, stream>>>(src, dst, cursor, part,
                                                         ovf_cnt, ovf, E, NB);
  k_fill2<<<NB, 256, 0, stream>>>(part, cursor, col, cnt, dinv, ovf_cnt, ovf, N);

  int gblocks = (N + 127) / 128;
  int ablocks = (N + 3) / 4;
  k_gemm<256><<<gblocks, 256, 0, stream>>>(x, W1, dinv, hb, N);
  k_agg<<<ablocks, 256, 0, stream>>>(hb, cnt, col, dinv, ovf_cnt, ovf, b1, aggbuf, N);
  k_gemm<128><<<gblocks, 256, 0, stream>>>(aggbuf, W2, dinv, hb, N);
  k_agg<<<ablocks, 256, 0, stream>>>(hb, cnt, col, dinv, ovf_cnt, ovf, b2, out, N);
}

// Round 6
// 298.830 us; speedup vs baseline: 1.7105x; 1.1297x over previous
//
#include <hip/hip_runtime.h>
#include <cstdint>
#include <cstddef>

// ---------------------------------------------------------------------------
// 2-layer GCN, round 6: MFMA bf16 GEMMs (no LDS), bf16 inter-layer buffers.
//   memset -> k_part -> k_fill2 (ELL build, cnt+dinv)
//   k_cvt_w: W1,W2 fp32 -> transposed bf16 WT[N][K]
//   k_gemm_mfma<256,AF32=1>: hb = bf16((x@W1)*dinv[row])   [N][128] bf16
//   k_agg<BF16OUT=1>      : agg1 = relu(...) as bf16       [N][128] bf16
//   k_gemm_mfma<128,AF32=0>: hb = bf16((agg1@W2)*dinv[row])
//   k_agg<BF16OUT=0>      : out  = relu(...) fp32
// ---------------------------------------------------------------------------

#define ELL_STRIDE 128
#define BCAP 8192
#define OVF_CAP 1024
#define PART_T 4096

typedef __attribute__((ext_vector_type(8))) short bf16x8;
typedef __attribute__((ext_vector_type(4))) float floatx4;

__device__ __forceinline__ unsigned short f2bf(float f) {
  unsigned int u = __float_as_uint(f);
  unsigned int r = (u + 0x7fffu + ((u >> 16) & 1u)) >> 16;   // RNE
  return (unsigned short)r;
}
__device__ __forceinline__ float2 bfpair(unsigned int p) {
  float2 r;
  r.x = __uint_as_float(p << 16);
  r.y = __uint_as_float(p & 0xffff0000u);
  return r;
}

// ---------------- phase 1: bucket partition ----------------
__global__ __launch_bounds__(256) void k_part(const int* __restrict__ src,
                                              const int* __restrict__ dst,
                                              int* __restrict__ cursor,
                                              unsigned int* __restrict__ part,
                                              int* __restrict__ ovf_cnt,
                                              int* __restrict__ ovf,
                                              int E, int NB) {
  __shared__ unsigned int stage1[PART_T];
  __shared__ unsigned int stage2[PART_T];
  __shared__ int hist[512];
  __shared__ int base_g[512];
  __shared__ int base_l[512];
  __shared__ int cl[512];
  const int tid = threadIdx.x;
  const int e0 = blockIdx.x * PART_T;
  int valid = E - e0; if (valid > PART_T) valid = PART_T;

  for (int b = tid; b < NB; b += 256) { hist[b] = 0; cl[b] = 0; }
  __syncthreads();
  for (int i = tid; i < valid; i += 256) {
    int e = e0 + i;
    unsigned int v = (unsigned int)(src[e] & 0xffff) | ((unsigned int)dst[e] << 16);
    stage1[i] = v;
    atomicAdd(&hist[(v >> 16) >> 7], 1);
  }
  __syncthreads();
  for (int b = tid; b < NB; b += 256) base_g[b] = atomicAdd(&cursor[b], hist[b]);
  if (tid == 0) {
    int run = 0;
    for (int b = 0; b < NB; ++b) { base_l[b] = run; run += hist[b]; }
  }
  __syncthreads();
  for (int i = tid; i < valid; i += 256) {
    unsigned int v = stage1[i];
    int b = (v >> 16) >> 7;
    int pos = base_l[b] + atomicAdd(&cl[b], 1);
    stage2[pos] = v;
  }
  __syncthreads();
  for (int i = tid; i < valid; i += 256) {
    unsigned int v = stage2[i];
    int b = (v >> 16) >> 7;
    int g = base_g[b] + (i - base_l[b]);
    if (g < BCAP) {
      part[(size_t)b * BCAP + g] = v;
    } else {
      int p = atomicAdd(ovf_cnt, 1);
      if (p < OVF_CAP) { ovf[2 * p] = (int)(v & 0xffffu); ovf[2 * p + 1] = (int)(v >> 16); }
    }
  }
}

// ---------------- phase 2: per-bucket ELL build in LDS ----------------
__global__ __launch_bounds__(256) void k_fill2(const unsigned int* __restrict__ part,
                                               const int* __restrict__ cursor,
                                               unsigned short* __restrict__ col,
                                               int* __restrict__ cnt,
                                               float* __restrict__ dinv,
                                               int* __restrict__ ovf_cnt,
                                               int* __restrict__ ovf, int N) {
  __shared__ unsigned short slab[128 * ELL_STRIDE];  // 32 KB
  __shared__ int cl[128];
  const int tid = threadIdx.x;
  const int b = blockIdx.x;
  if (tid < 128) cl[tid] = 0;
  __syncthreads();
  int count = cursor[b]; if (count > BCAP) count = BCAP;
  const unsigned int* p = part + (size_t)b * BCAP;
  for (int i = tid; i < count; i += 256) {
    unsigned int v = p[i];
    int row = (v >> 16) & 127;
    int k = atomicAdd(&cl[row], 1);
    if (k < ELL_STRIDE) {
      slab[row * ELL_STRIDE + k] = (unsigned short)(v & 0xffffu);
    } else {
      int q = atomicAdd(ovf_cnt, 1);
      if (q < OVF_CAP) { ovf[2 * q] = (int)(v & 0xffffu); ovf[2 * q + 1] = (int)(v >> 16); }
    }
  }
  __syncthreads();
  uint4* d4 = (uint4*)(col + (size_t)b * 128 * ELL_STRIDE);
  const uint4* s4 = (const uint4*)slab;
  #pragma unroll
  for (int i = 0; i < (128 * ELL_STRIDE * 2) / (16 * 256); ++i)
    d4[i * 256 + tid] = s4[i * 256 + tid];
  if (tid < 128) {
    int node = b * 128 + tid;
    if (node < N) {
      int c = cl[tid];
      cnt[node] = c;
      dinv[node] = rsqrtf((float)c + 1.0f);
    }
  }
}

// ---------------- W -> bf16 transposed [N=128][K] ----------------
__global__ __launch_bounds__(256) void k_cvt_w(const float* __restrict__ W1,
                                               const float* __restrict__ W2,
                                               unsigned short* __restrict__ WT1,
                                               unsigned short* __restrict__ WT2) {
  int i = blockIdx.x * 256 + threadIdx.x;
  if (i < 128 * 256) {                 // WT1[n][k] = W1[k][n], K=256
    int n = i >> 8, k = i & 255;
    WT1[i] = f2bf(W1[k * 128 + n]);
  } else {
    int j = i - 128 * 256;
    if (j < 128 * 128) {               // WT2[n][k] = W2[k][n], K=128
      int n = j >> 7, k = j & 127;
      WT2[j] = f2bf(W2[k * 128 + n]);
    }
  }
}

// ---------------- MFMA GEMM: hb[M][128] = bf16((A@W)*dinv[row]) ----------
// wave = 16-row strip x full N=128 (8 MFMA n-tiles), K-steps of 32.
// A layout per lane: A[m=lane&15][k = (lane>>4)*8 + j]  (8 contiguous k)
// B layout per lane: B[k = (lane>>4)*8 + j][n=lane&15]  -> WT[n][k] contiguous
// C layout: row = (lane>>4)*4 + reg, col = lane&15.
template <int K, bool AF32>
__global__ __launch_bounds__(256) void k_gemm_mfma(const void* __restrict__ Xv,
                                                   const unsigned short* __restrict__ WT,
                                                   const float* __restrict__ dinv,
                                                   unsigned short* __restrict__ hb,
                                                   int M) {
  const int tid = threadIdx.x;
  const int wave = tid >> 6, lane = tid & 63;
  const int q = lane >> 4, m = lane & 15;
  const int row0 = blockIdx.x * 64 + wave * 16;   // M % 16 == 0: strip valid or fully OOB
  if (row0 >= M) return;
  const int arow = row0 + m;

  floatx4 acc[8];
  #pragma unroll
  for (int nt = 0; nt < 8; ++nt) acc[nt] = (floatx4){0.f, 0.f, 0.f, 0.f};

  #pragma unroll
  for (int ks = 0; ks < K / 32; ++ks) {
    const int k0 = ks * 32 + q * 8;
    bf16x8 af;
    if (AF32) {
      const float* X = (const float*)Xv;
      float4 a0 = *(const float4*)(X + (size_t)arow * K + k0);
      float4 a1 = *(const float4*)(X + (size_t)arow * K + k0 + 4);
      unsigned short u0 = f2bf(a0.x), u1 = f2bf(a0.y), u2 = f2bf(a0.z), u3 = f2bf(a0.w);
      unsigned short u4 = f2bf(a1.x), u5 = f2bf(a1.y), u6 = f2bf(a1.z), u7 = f2bf(a1.w);
      af = (bf16x8){(short)u0, (short)u1, (short)u2, (short)u3,
                    (short)u4, (short)u5, (short)u6, (short)u7};
    } else {
      af = *(const bf16x8*)((const unsigned short*)Xv + (size_t)arow * K + k0);
    }
    #pragma unroll
    for (int nt = 0; nt < 8; ++nt) {
      bf16x8 bf = *(const bf16x8*)(WT + (size_t)(nt * 16 + m) * K + k0);
      acc[nt] = __builtin_amdgcn_mfma_f32_16x16x32_bf16(af, bf, acc[nt], 0, 0, 0);
    }
  }
  #pragma unroll
  for (int r = 0; r < 4; ++r) {
    int grow = row0 + q * 4 + r;
    float di = dinv[grow];
    #pragma unroll
    for (int nt = 0; nt < 8; ++nt)
      hb[(size_t)grow * 128 + nt * 16 + m] = f2bf(acc[nt][r] * di);
  }
}

// ---------------- ELL gather-aggregate + bias + ReLU ----------------
// wave = 1 dst node; lane = uint (2 channels) of the 256B bf16 row.
template <bool BF16OUT>
__global__ __launch_bounds__(256) void k_agg(const unsigned int* __restrict__ hb,
                                             const int* __restrict__ cnt,
                                             const unsigned short* __restrict__ col,
                                             const float* __restrict__ dinv,
                                             const int* __restrict__ ovf_cnt,
                                             const int* __restrict__ ovf,
                                             const float* __restrict__ bias,
                                             void* __restrict__ outv, int n) {
  const int wave = threadIdx.x >> 6;
  const int lane = threadIdx.x & 63;
  const int d = blockIdx.x * 4 + wave;
  if (d >= n) return;

  // self-loop: hb pre-scaled by dinv, so hb[d]*dinv[d] = h[d]*dinv^2
  float2 acc = bfpair(hb[(size_t)d * 64 + lane]);

  int m = cnt[d]; if (m > ELL_STRIDE) m = ELL_STRIDE;
  const unsigned short* crow = col + (size_t)d * ELL_STRIDE;
  int k = 0;
  for (; k + 8 <= m; k += 8) {
    ushort4 ca = *(const ushort4*)(crow + k);
    ushort4 cb = *(const ushort4*)(crow + k + 4);
    unsigned int p0 = hb[(size_t)ca.x * 64 + lane];
    unsigned int p1 = hb[(size_t)ca.y * 64 + lane];
    unsigned int p2 = hb[(size_t)ca.z * 64 + lane];
    unsigned int p3 = hb[(size_t)ca.w * 64 + lane];
    unsigned int p4 = hb[(size_t)cb.x * 64 + lane];
    unsigned int p5 = hb[(size_t)cb.y * 64 + lane];
    unsigned int p6 = hb[(size_t)cb.z * 64 + lane];
    unsigned int p7 = hb[(size_t)cb.w * 64 + lane];
    float2 v0 = bfpair(p0), v1 = bfpair(p1), v2 = bfpair(p2), v3 = bfpair(p3);
    float2 v4 = bfpair(p4), v5 = bfpair(p5), v6 = bfpair(p6), v7 = bfpair(p7);
    acc.x += v0.x + v1.x + v2.x + v3.x;
    acc.y += v0.y + v1.y + v2.y + v3.y;
    acc.x += v4.x + v5.x + v6.x + v7.x;
    acc.y += v4.y + v5.y + v6.y + v7.y;
  }
  for (; k < m; ++k) {
    int c = crow[k];
    float2 v = bfpair(hb[(size_t)c * 64 + lane]);
    acc.x += v.x; acc.y += v.y;
  }
  int V = *ovf_cnt; if (V > OVF_CAP) V = OVF_CAP;
  for (int j = 0; j < V; ++j) {
    if (ovf[2 * j + 1] == d) {
      float2 v = bfpair(hb[(size_t)ovf[2 * j] * 64 + lane]);
      acc.x += v.x; acc.y += v.y;
    }
  }
  float di = dinv[d];
  float2 bv = *(const float2*)(bias + lane * 2);
  float rx = di * acc.x + bv.x;
  float ry = di * acc.y + bv.y;
  rx = rx > 0.f ? rx : 0.f;
  ry = ry > 0.f ? ry : 0.f;
  if (BF16OUT) {
    unsigned int pk = (unsigned int)f2bf(rx) | ((unsigned int)f2bf(ry) << 16);
    ((unsigned int*)outv)[(size_t)d * 64 + lane] = pk;
  } else {
    *(float2*)((float*)outv + (size_t)d * 128 + lane * 2) = make_float2(rx, ry);
  }
}

// ---------------------------------------------------------------------------
extern "C" void kernel_launch(void* const* d_in, const int* in_sizes, int n_in,
                              void* d_out, int out_size, void* d_ws, size_t ws_size,
                              hipStream_t stream) {
  const float* x  = (const float*)d_in[0];
  const int*   ei = (const int*)d_in[1];
  const float* W1 = (const float*)d_in[2];
  const float* b1 = (const float*)d_in[3];
  const float* W2 = (const float*)d_in[4];
  const float* b2 = (const float*)d_in[5];
  float* out = (float*)d_out;

  const int IN_CH = 256;
  const int N = in_sizes[0] / IN_CH;   // 50000
  const int E = in_sizes[1] / 2;       // 1,600,000
  const int NB = (N + 127) >> 7;       // 391 buckets

  const int* src = ei;
  const int* dst = ei + E;

  char* ws = (char*)d_ws;
  size_t off = 0;
  auto carve = [&](size_t bytes) {
    void* p = ws + off;
    off += (bytes + 255) & ~(size_t)255;
    return p;
  };
  int*            cursor  = (int*)carve((size_t)NB * 4);
  int*            ovf_cnt = (int*)carve(4);
  size_t zero_bytes = off;                        // cursor + ovf_cnt
  int*            ovf     = (int*)carve((size_t)OVF_CAP * 2 * 4);
  int*            cnt     = (int*)carve((size_t)N * 4);
  float*          dinv    = (float*)carve((size_t)N * 4);
  unsigned short* col     = (unsigned short*)carve((size_t)NB * 128 * ELL_STRIDE * 2);
  unsigned short* hb      = (unsigned short*)carve((size_t)N * 128 * 2);  // [N][128] bf16
  unsigned short* WT1     = (unsigned short*)carve(128 * 256 * 2);
  unsigned short* WT2     = (unsigned short*)carve(128 * 128 * 2);
  // union: part (dead after k_fill2) aliases aggbuf (bf16, written by k_agg#1)
  char*           unionp  = (char*)carve((size_t)NB * BCAP * 4);   // 12.8MB >= aggbuf 12.8MB
  unsigned int*   part    = (unsigned int*)unionp;
  unsigned short* aggbuf  = (unsigned short*)unionp;

  hipMemsetAsync(d_ws, 0, zero_bytes, stream);

  k_part <<<(E + PART_T - 1) / PART_T, 256, 0, stream>>>(src, dst, cursor, part,
                                                         ovf_cnt, ovf, E, NB);
  k_fill2<<<NB, 256, 0, stream>>>(part, cursor, col, cnt, dinv, ovf_cnt, ovf, N);
  k_cvt_w<<<(128 * 256 + 128 * 128 + 255) / 256, 256, 0, stream>>>(W1, W2, WT1, WT2);

  int gblocks = (N + 63) / 64;         // 782
  int ablocks = (N + 3) / 4;
  k_gemm_mfma<256, true ><<<gblocks, 256, 0, stream>>>(x, WT1, dinv, hb, N);
  k_agg<true ><<<ablocks, 256, 0, stream>>>((const unsigned int*)hb, cnt, col, dinv,
                                            ovf_cnt, ovf, b1, aggbuf, N);
  k_gemm_mfma<128, false><<<gblocks, 256, 0, stream>>>(aggbuf, WT2, dinv, hb, N);
  k_agg<false><<<ablocks, 256, 0, stream>>>((const unsigned int*)hb, cnt, col, dinv,
                                            ovf_cnt, ovf, b2, out, N);
}

// Round 8
// 295.603 us; speedup vs baseline: 1.7292x; 1.0109x over previous
//
#include <hip/hip_runtime.h>
#include <cstdint>
#include <cstddef>

// ---------------------------------------------------------------------------
// 2-layer GCN, round 8: bf16 messages (r6 precision), ELL-64, A-prefetch MFMA
// GEMM (MLP fix), parallel scan in k_part, memset folded into k_cvt_w.
//   k_cvt_w: zero cursor/ovf_cnt + W1,W2 -> bf16 WT[N][K]
//   k_part : bucket partition of packed (src,dst) u16 pairs
//   k_fill2: per-bucket ELL-64 build in LDS, emits cnt+dinv
//   k_gemm_mfma<256,AF32>: hb = bf16((x@W1)*dinv[row])  [N][128] bf16
//   k_agg<BF16OUT=1>, k_gemm_mfma<128>, k_agg<BF16OUT=0>
// ---------------------------------------------------------------------------

#define ELL_STRIDE 64
#define BCAP 8192
#define OVF_CAP 1024
#define PART_T 4096

typedef __attribute__((ext_vector_type(8))) short bf16x8;
typedef __attribute__((ext_vector_type(4))) float floatx4;

__device__ __forceinline__ unsigned short f2bf(float f) {
  unsigned int u = __float_as_uint(f);
  unsigned int r = (u + 0x7fffu + ((u >> 16) & 1u)) >> 16;   // RNE
  return (unsigned short)r;
}
__device__ __forceinline__ float2 bfpair(unsigned int p) {
  float2 r;
  r.x = __uint_as_float(p << 16);
  r.y = __uint_as_float(p & 0xffff0000u);
  return r;
}

// ---------------- zero workspace + W -> bf16 transposed [N=128][K] --------
__global__ __launch_bounds__(256) void k_cvt_w(const float* __restrict__ W1,
                                               const float* __restrict__ W2,
                                               unsigned short* __restrict__ WT1,
                                               unsigned short* __restrict__ WT2,
                                               int* __restrict__ cursor,
                                               int* __restrict__ ovf_cnt,
                                               int NB) {
  int i = blockIdx.x * 256 + threadIdx.x;
  if (i < NB) cursor[i] = 0;
  if (i == NB) *ovf_cnt = 0;
  if (i < 128 * 256) {                 // WT1[n][k] = W1[k][n], K=256
    int n = i >> 8, k = i & 255;
    WT1[i] = f2bf(W1[k * 128 + n]);
  } else if (i < 128 * 256 + 128 * 128) {
    int j = i - 128 * 256;             // WT2[n][k] = W2[k][n], K=128
    int n = j >> 7, k = j & 127;
    WT2[j] = f2bf(W2[k * 128 + n]);
  }
}

// ---------------- phase 1: bucket partition ----------------
__global__ __launch_bounds__(256) void k_part(const int* __restrict__ src,
                                              const int* __restrict__ dst,
                                              int* __restrict__ cursor,
                                              unsigned int* __restrict__ part,
                                              int* __restrict__ ovf_cnt,
                                              int* __restrict__ ovf,
                                              int E, int NB) {
  __shared__ unsigned int stage1[PART_T];
  __shared__ unsigned int stage2[PART_T];
  __shared__ int hist[512];
  __shared__ int base_g[512];
  __shared__ int base_l[512];
  __shared__ int cl[512];
  __shared__ int sc[256];
  const int tid = threadIdx.x;
  const int e0 = blockIdx.x * PART_T;
  int valid = E - e0; if (valid > PART_T) valid = PART_T;

  hist[tid] = 0; hist[tid + 256] = 0;
  cl[tid] = 0; cl[tid + 256] = 0;
  __syncthreads();
  for (int i = tid; i < valid; i += 256) {
    int e = e0 + i;
    unsigned int v = (unsigned int)(src[e] & 0xffff) | ((unsigned int)dst[e] << 16);
    stage1[i] = v;
    atomicAdd(&hist[(v >> 16) >> 7], 1);
  }
  __syncthreads();
  for (int b = tid; b < NB; b += 256) base_g[b] = atomicAdd(&cursor[b], hist[b]);
  // parallel exclusive scan of hist[0..511] (each thread owns slots 2t,2t+1)
  int h0 = hist[2 * tid], h1 = hist[2 * tid + 1];
  int pv = h0 + h1;
  sc[tid] = pv;
  __syncthreads();
  #pragma unroll
  for (int off = 1; off < 256; off <<= 1) {
    int t = (tid >= off) ? sc[tid - off] : 0;
    __syncthreads();
    sc[tid] += t;
    __syncthreads();
  }
  int excl = sc[tid] - pv;
  base_l[2 * tid] = excl;
  base_l[2 * tid + 1] = excl + h0;
  __syncthreads();
  for (int i = tid; i < valid; i += 256) {
    unsigned int v = stage1[i];
    int b = (v >> 16) >> 7;
    int pos = base_l[b] + atomicAdd(&cl[b], 1);
    stage2[pos] = v;
  }
  __syncthreads();
  // copy out: consecutive i within a bucket run -> consecutive global addrs
  for (int i = tid; i < valid; i += 256) {
    unsigned int v = stage2[i];
    int b = (v >> 16) >> 7;
    int g = base_g[b] + (i - base_l[b]);
    if (g < BCAP) {
      part[(size_t)b * BCAP + g] = v;
    } else {
      int p = atomicAdd(ovf_cnt, 1);
      if (p < OVF_CAP) { ovf[2 * p] = (int)(v & 0xffffu); ovf[2 * p + 1] = (int)(v >> 16); }
    }
  }
}

// ---------------- phase 2: per-bucket ELL build in LDS ----------------
__global__ __launch_bounds__(256) void k_fill2(const unsigned int* __restrict__ part,
                                               const int* __restrict__ cursor,
                                               unsigned short* __restrict__ col,
                                               int* __restrict__ cnt,
                                               float* __restrict__ dinv,
                                               int* __restrict__ ovf_cnt,
                                               int* __restrict__ ovf, int N) {
  __shared__ unsigned short slab[128 * ELL_STRIDE];  // 16 KB
  __shared__ int cl[128];
  const int tid = threadIdx.x;
  const int b = blockIdx.x;
  if (tid < 128) cl[tid] = 0;
  __syncthreads();
  int count = cursor[b]; if (count > BCAP) count = BCAP;
  const unsigned int* p = part + (size_t)b * BCAP;
  for (int i = tid; i < count; i += 256) {
    unsigned int v = p[i];
    int row = (v >> 16) & 127;
    int k = atomicAdd(&cl[row], 1);
    if (k < ELL_STRIDE) {
      slab[row * ELL_STRIDE + k] = (unsigned short)(v & 0xffffu);
    } else {
      int q = atomicAdd(ovf_cnt, 1);
      if (q < OVF_CAP) { ovf[2 * q] = (int)(v & 0xffffu); ovf[2 * q + 1] = (int)(v >> 16); }
    }
  }
  __syncthreads();
  uint4* d4 = (uint4*)(col + (size_t)b * 128 * ELL_STRIDE);
  const uint4* s4 = (const uint4*)slab;
  #pragma unroll
  for (int i = 0; i < (128 * ELL_STRIDE * 2) / (16 * 256); ++i)
    d4[i * 256 + tid] = s4[i * 256 + tid];
  if (tid < 128) {
    int node = b * 128 + tid;
    if (node < N) {
      int c = cl[tid];
      cnt[node] = c;
      dinv[node] = rsqrtf((float)c + 1.0f);
    }
  }
}

// ---------------- MFMA GEMM: hb[M][128] = bf16((A@W)*dinv[row]) ----------
// wave = 16-row strip x N=128 (8 n-tiles). ALL A-fragments prefetched up
// front (K/32 independent loads -> MLP, HBM latency paid once per wave).
template <int K, bool AF32>
__global__ __launch_bounds__(256) void k_gemm_mfma(const void* __restrict__ Xv,
                                                   const unsigned short* __restrict__ WT,
                                                   const float* __restrict__ dinv,
                                                   unsigned short* __restrict__ hb,
                                                   int M) {
  const int tid = threadIdx.x;
  const int wave = tid >> 6, lane = tid & 63;
  const int q = lane >> 4, m = lane & 15;
  const int row0 = blockIdx.x * 64 + wave * 16;   // M % 16 == 0
  if (row0 >= M) return;
  const int arow = row0 + m;

  bf16x8 af[K / 32];
  if (AF32) {
    const float* X = (const float*)Xv;
    float4 a[2 * (K / 32)];
    #pragma unroll
    for (int ks = 0; ks < K / 32; ++ks) {
      a[2 * ks]     = *(const float4*)(X + (size_t)arow * K + ks * 32 + q * 8);
      a[2 * ks + 1] = *(const float4*)(X + (size_t)arow * K + ks * 32 + q * 8 + 4);
    }
    #pragma unroll
    for (int ks = 0; ks < K / 32; ++ks) {
      af[ks] = (bf16x8){(short)f2bf(a[2 * ks].x),     (short)f2bf(a[2 * ks].y),
                        (short)f2bf(a[2 * ks].z),     (short)f2bf(a[2 * ks].w),
                        (short)f2bf(a[2 * ks + 1].x), (short)f2bf(a[2 * ks + 1].y),
                        (short)f2bf(a[2 * ks + 1].z), (short)f2bf(a[2 * ks + 1].w)};
    }
  } else {
    #pragma unroll
    for (int ks = 0; ks < K / 32; ++ks)
      af[ks] = *(const bf16x8*)((const unsigned short*)Xv +
                                (size_t)arow * K + ks * 32 + q * 8);
  }

  floatx4 acc[8];
  #pragma unroll
  for (int nt = 0; nt < 8; ++nt) acc[nt] = (floatx4){0.f, 0.f, 0.f, 0.f};
  #pragma unroll
  for (int ks = 0; ks < K / 32; ++ks) {
    const int k0 = ks * 32 + q * 8;
    #pragma unroll
    for (int nt = 0; nt < 8; ++nt) {
      bf16x8 bf = *(const bf16x8*)(WT + (size_t)(nt * 16 + m) * K + k0);
      acc[nt] = __builtin_amdgcn_mfma_f32_16x16x32_bf16(af[ks], bf, acc[nt], 0, 0, 0);
    }
  }
  #pragma unroll
  for (int r = 0; r < 4; ++r) {
    int grow = row0 + q * 4 + r;
    float di = dinv[grow];
    #pragma unroll
    for (int nt = 0; nt < 8; ++nt)
      hb[(size_t)grow * 128 + nt * 16 + m] = f2bf(acc[nt][r] * di);
  }
}

// ---------------- ELL gather-aggregate + bias + ReLU ----------------
// wave = 1 dst node; lane = uint (2 channels) of the 256B bf16 row; 8-deep
// unrolled edge loop -> 8 independent full-row gathers in flight.
template <bool BF16OUT>
__global__ __launch_bounds__(256) void k_agg(const unsigned int* __restrict__ hb,
                                             const int* __restrict__ cnt,
                                             const unsigned short* __restrict__ col,
                                             const float* __restrict__ dinv,
                                             const int* __restrict__ ovf_cnt,
                                             const int* __restrict__ ovf,
                                             const float* __restrict__ bias,
                                             void* __restrict__ outv, int n) {
  const int wave = threadIdx.x >> 6;
  const int lane = threadIdx.x & 63;
  const int d = blockIdx.x * 4 + wave;
  if (d >= n) return;

  // self-loop: hb pre-scaled by dinv, so hb[d]*dinv[d] = h[d]*dinv^2
  float2 acc = bfpair(hb[(size_t)d * 64 + lane]);

  int m = cnt[d]; if (m > ELL_STRIDE) m = ELL_STRIDE;
  const unsigned short* crow = col + (size_t)d * ELL_STRIDE;
  int k = 0;
  for (; k + 8 <= m; k += 8) {
    ushort4 ca = *(const ushort4*)(crow + k);
    ushort4 cb = *(const ushort4*)(crow + k + 4);
    unsigned int p0 = hb[(size_t)ca.x * 64 + lane];
    unsigned int p1 = hb[(size_t)ca.y * 64 + lane];
    unsigned int p2 = hb[(size_t)ca.z * 64 + lane];
    unsigned int p3 = hb[(size_t)ca.w * 64 + lane];
    unsigned int p4 = hb[(size_t)cb.x * 64 + lane];
    unsigned int p5 = hb[(size_t)cb.y * 64 + lane];
    unsigned int p6 = hb[(size_t)cb.z * 64 + lane];
    unsigned int p7 = hb[(size_t)cb.w * 64 + lane];
    float2 v0 = bfpair(p0), v1 = bfpair(p1), v2 = bfpair(p2), v3 = bfpair(p3);
    float2 v4 = bfpair(p4), v5 = bfpair(p5), v6 = bfpair(p6), v7 = bfpair(p7);
    acc.x += v0.x + v1.x + v2.x + v3.x;
    acc.y += v0.y + v1.y + v2.y + v3.y;
    acc.x += v4.x + v5.x + v6.x + v7.x;
    acc.y += v4.y + v5.y + v6.y + v7.y;
  }
  for (; k < m; ++k) {
    int c = crow[k];
    float2 v = bfpair(hb[(size_t)c * 64 + lane]);
    acc.x += v.x; acc.y += v.y;
  }
  int V = *ovf_cnt; if (V > OVF_CAP) V = OVF_CAP;
  for (int j = 0; j < V; ++j) {
    if (ovf[2 * j + 1] == d) {
      float2 v = bfpair(hb[(size_t)ovf[2 * j] * 64 + lane]);
      acc.x += v.x; acc.y += v.y;
    }
  }
  float di = dinv[d];
  float2 bv = *(const float2*)(bias + lane * 2);
  float rx = di * acc.x + bv.x;
  float ry = di * acc.y + bv.y;
  rx = rx > 0.f ? rx : 0.f;
  ry = ry > 0.f ? ry : 0.f;
  if (BF16OUT) {
    unsigned int pk = (unsigned int)f2bf(rx) | ((unsigned int)f2bf(ry) << 16);
    ((unsigned int*)outv)[(size_t)d * 64 + lane] = pk;
  } else {
    *(float2*)((float*)outv + (size_t)d * 128 + lane * 2) = make_float2(rx, ry);
  }
}

// ---------------------------------------------------------------------------
extern "C" void kernel_launch(void* const* d_in, const int* in_sizes, int n_in,
                              void* d_out, int out_size, void* d_ws, size_t ws_size,
                              hipStream_t stream) {
  const float* x  = (const float*)d_in[0];
  const int*   ei = (const int*)d_in[1];
  const float* W1 = (const float*)d_in[2];
  const float* b1 = (const float*)d_in[3];
  const float* W2 = (const float*)d_in[4];
  const float* b2 = (const float*)d_in[5];
  float* out = (float*)d_out;

  const int IN_CH = 256;
  const int N = in_sizes[0] / IN_CH;   // 50000
  const int E = in_sizes[1] / 2;       // 1,600,000
  const int NB = (N + 127) >> 7;       // 391 buckets

  const int* src = ei;
  const int* dst = ei + E;

  char* ws = (char*)d_ws;
  size_t off = 0;
  auto carve = [&](size_t bytes) {
    void* p = ws + off;
    off += (bytes + 255) & ~(size_t)255;
    return p;
  };
  int*            cursor  = (int*)carve((size_t)NB * 4);
  int*            ovf_cnt = (int*)carve(4);
  int*            ovf     = (int*)carve((size_t)OVF_CAP * 2 * 4);
  int*            cnt     = (int*)carve((size_t)N * 4);
  float*          dinv    = (float*)carve((size_t)N * 4);
  unsigned short* col     = (unsigned short*)carve((size_t)N * ELL_STRIDE * 2); // 6.4MB
  unsigned short* hb      = (unsigned short*)carve((size_t)N * 128 * 2);        // 12.8MB
  unsigned short* WT1     = (unsigned short*)carve(128 * 256 * 2);
  unsigned short* WT2     = (unsigned short*)carve(128 * 128 * 2);
  // union: part (dead after k_fill2) aliases aggbuf (bf16, by k_agg#1)
  char*           unionp  = (char*)carve((size_t)NB * BCAP * 4);   // 12.8MB
  unsigned int*   part    = (unsigned int*)unionp;
  unsigned short* aggbuf  = (unsigned short*)unionp;               // [N][128] bf16

  k_cvt_w<<<(128 * 256 + 128 * 128 + 255) / 256, 256, 0, stream>>>(
      W1, W2, WT1, WT2, cursor, ovf_cnt, NB);
  k_part <<<(E + PART_T - 1) / PART_T, 256, 0, stream>>>(src, dst, cursor, part,
                                                         ovf_cnt, ovf, E, NB);
  k_fill2<<<NB, 256, 0, stream>>>(part, cursor, col, cnt, dinv, ovf_cnt, ovf, N);

  int gblocks = (N + 63) / 64;         // 782
  int ablocks = (N + 3) / 4;           // 12500
  k_gemm_mfma<256, true ><<<gblocks, 256, 0, stream>>>(x, WT1, dinv, hb, N);
  k_agg<true ><<<ablocks, 256, 0, stream>>>((const unsigned int*)hb, cnt, col, dinv,
                                            ovf_cnt, ovf, b1, aggbuf, N);
  k_gemm_mfma<128, false><<<gblocks, 256, 0, stream>>>(aggbuf, WT2, dinv, hb, N);
  k_agg<false><<<ablocks, 256, 0, stream>>>((const unsigned int*)hb, cnt, col, dinv,
                                            ovf_cnt, ovf, b2, out, N);
}

// Round 9
// 262.542 us; speedup vs baseline: 1.9469x; 1.1259x over previous
//
#include <hip/hip_runtime.h>
#include <cstdint>
#include <cstddef>

// ---------------------------------------------------------------------------
// 2-layer GCN, round 9: LDS-staged-B MFMA GEMM, 16-deep agg MLP, finer k_part.
//   k_cvt_w: zero cursor/ovf_cnt + W1,W2 -> bf16 WT[N][K]
//   k_part : bucket partition of packed (src,dst) u16 pairs (2048/block)
//   k_fill2: per-bucket ELL-64 build in LDS, emits cnt+dinv
//   k_gemm_mfma<256,AF32>: hb = bf16((x@W1)*dinv[row]); B staged in LDS
//   k_agg<BF16OUT=1>, k_gemm_mfma<128>, k_agg<BF16OUT=0>
// ---------------------------------------------------------------------------

#define ELL_STRIDE 64
#define BCAP 8192
#define OVF_CAP 1024
#define PART_T 2048

typedef __attribute__((ext_vector_type(8))) short bf16x8;
typedef __attribute__((ext_vector_type(4))) float floatx4;

__device__ __forceinline__ unsigned short f2bf(float f) {
  unsigned int u = __float_as_uint(f);
  unsigned int r = (u + 0x7fffu + ((u >> 16) & 1u)) >> 16;   // RNE
  return (unsigned short)r;
}
__device__ __forceinline__ float2 bfpair(unsigned int p) {
  float2 r;
  r.x = __uint_as_float(p << 16);
  r.y = __uint_as_float(p & 0xffff0000u);
  return r;
}

// ---------------- zero workspace + W -> bf16 transposed [N=128][K] --------
__global__ __launch_bounds__(256) void k_cvt_w(const float* __restrict__ W1,
                                               const float* __restrict__ W2,
                                               unsigned short* __restrict__ WT1,
                                               unsigned short* __restrict__ WT2,
                                               int* __restrict__ cursor,
                                               int* __restrict__ ovf_cnt,
                                               int NB) {
  int i = blockIdx.x * 256 + threadIdx.x;
  if (i < NB) cursor[i] = 0;
  if (i == NB) *ovf_cnt = 0;
  if (i < 128 * 256) {                 // WT1[n][k] = W1[k][n], K=256
    int n = i >> 8, k = i & 255;
    WT1[i] = f2bf(W1[k * 128 + n]);
  } else if (i < 128 * 256 + 128 * 128) {
    int j = i - 128 * 256;             // WT2[n][k] = W2[k][n], K=128
    int n = j >> 7, k = j & 127;
    WT2[j] = f2bf(W2[k * 128 + n]);
  }
}

// ---------------- phase 1: bucket partition ----------------
__global__ __launch_bounds__(256) void k_part(const int* __restrict__ src,
                                              const int* __restrict__ dst,
                                              int* __restrict__ cursor,
                                              unsigned int* __restrict__ part,
                                              int* __restrict__ ovf_cnt,
                                              int* __restrict__ ovf,
                                              int E, int NB) {
  __shared__ unsigned int stage1[PART_T];
  __shared__ unsigned int stage2[PART_T];
  __shared__ int hist[512];
  __shared__ int base_g[512];
  __shared__ int base_l[512];
  __shared__ int cl[512];
  __shared__ int sc[256];
  const int tid = threadIdx.x;
  const int e0 = blockIdx.x * PART_T;
  int valid = E - e0; if (valid > PART_T) valid = PART_T;

  hist[tid] = 0; hist[tid + 256] = 0;
  cl[tid] = 0; cl[tid + 256] = 0;
  __syncthreads();
  for (int i = tid; i < valid; i += 256) {
    int e = e0 + i;
    unsigned int v = (unsigned int)(src[e] & 0xffff) | ((unsigned int)dst[e] << 16);
    stage1[i] = v;
    atomicAdd(&hist[(v >> 16) >> 7], 1);
  }
  __syncthreads();
  for (int b = tid; b < NB; b += 256) base_g[b] = atomicAdd(&cursor[b], hist[b]);
  // parallel exclusive scan of hist[0..511] (thread t owns slots 2t, 2t+1)
  int h0 = hist[2 * tid], h1 = hist[2 * tid + 1];
  int pv = h0 + h1;
  sc[tid] = pv;
  __syncthreads();
  #pragma unroll
  for (int off = 1; off < 256; off <<= 1) {
    int t = (tid >= off) ? sc[tid - off] : 0;
    __syncthreads();
    sc[tid] += t;
    __syncthreads();
  }
  int excl = sc[tid] - pv;
  base_l[2 * tid] = excl;
  base_l[2 * tid + 1] = excl + h0;
  __syncthreads();
  for (int i = tid; i < valid; i += 256) {
    unsigned int v = stage1[i];
    int b = (v >> 16) >> 7;
    int pos = base_l[b] + atomicAdd(&cl[b], 1);
    stage2[pos] = v;
  }
  __syncthreads();
  for (int i = tid; i < valid; i += 256) {
    unsigned int v = stage2[i];
    int b = (v >> 16) >> 7;
    int g = base_g[b] + (i - base_l[b]);
    if (g < BCAP) {
      part[(size_t)b * BCAP + g] = v;
    } else {
      int p = atomicAdd(ovf_cnt, 1);
      if (p < OVF_CAP) { ovf[2 * p] = (int)(v & 0xffffu); ovf[2 * p + 1] = (int)(v >> 16); }
    }
  }
}

// ---------------- phase 2: per-bucket ELL build in LDS ----------------
__global__ __launch_bounds__(256) void k_fill2(const unsigned int* __restrict__ part,
                                               const int* __restrict__ cursor,
                                               unsigned short* __restrict__ col,
                                               int* __restrict__ cnt,
                                               float* __restrict__ dinv,
                                               int* __restrict__ ovf_cnt,
                                               int* __restrict__ ovf, int N) {
  __shared__ unsigned short slab[128 * ELL_STRIDE];  // 16 KB
  __shared__ int cl[128];
  const int tid = threadIdx.x;
  const int b = blockIdx.x;
  if (tid < 128) cl[tid] = 0;
  __syncthreads();
  int count = cursor[b]; if (count > BCAP) count = BCAP;
  const unsigned int* p = part + (size_t)b * BCAP;
  for (int i = tid; i < count; i += 256) {
    unsigned int v = p[i];
    int row = (v >> 16) & 127;
    int k = atomicAdd(&cl[row], 1);
    if (k < ELL_STRIDE) {
      slab[row * ELL_STRIDE + k] = (unsigned short)(v & 0xffffu);
    } else {
      int q = atomicAdd(ovf_cnt, 1);
      if (q < OVF_CAP) { ovf[2 * q] = (int)(v & 0xffffu); ovf[2 * q + 1] = (int)(v >> 16); }
    }
  }
  __syncthreads();
  uint4* d4 = (uint4*)(col + (size_t)b * 128 * ELL_STRIDE);
  const uint4* s4 = (const uint4*)slab;
  #pragma unroll
  for (int i = 0; i < (128 * ELL_STRIDE * 2) / (16 * 256); ++i)
    d4[i * 256 + tid] = s4[i * 256 + tid];
  if (tid < 128) {
    int node = b * 128 + tid;
    if (node < N) {
      int c = cl[tid];
      cnt[node] = c;
      dinv[node] = rsqrtf((float)c + 1.0f);
    }
  }
}

// ---------------- MFMA GEMM: hb[M][128] = bf16((A@W)*dinv[row]) ----------
// B (WT) staged in LDS in two 64-row halves, rows padded +8 shorts so the
// 16 m-lanes of a ds_read_b128 land on banks m*4%32 (2-way alias = free).
// A-fragments loaded/converted once (kept in regs across both halves).
template <int K, bool AF32>
__global__ __launch_bounds__(256) void k_gemm_mfma(const void* __restrict__ Xv,
                                                   const unsigned short* __restrict__ WT,
                                                   const float* __restrict__ dinv,
                                                   unsigned short* __restrict__ hb,
                                                   int M) {
  constexpr int KP = K + 8;
  __shared__ unsigned short Bs[64 * KP];
  const int tid = threadIdx.x;
  const int wave = tid >> 6, lane = tid & 63;
  const int q = lane >> 4, m = lane & 15;
  const int row0 = blockIdx.x * 64 + wave * 16;   // M % 16 == 0: strip valid or OOB
  const bool active = row0 < M;
  const int arow = row0 + m;

  floatx4 acc[8];
  #pragma unroll
  for (int nt = 0; nt < 8; ++nt) acc[nt] = (floatx4){0.f, 0.f, 0.f, 0.f};
  bf16x8 af[K / 32];

  #pragma unroll
  for (int half = 0; half < 2; ++half) {
    __syncthreads();   // (half 1) protect prior reads before overwrite
    for (int c = tid; c < 64 * (K / 8); c += 256) {
      int r = c / (K / 8), ko = (c % (K / 8)) * 8;
      *(uint4*)(Bs + r * KP + ko) =
          *(const uint4*)(WT + (size_t)(half * 64 + r) * K + ko);
    }
    __syncthreads();
    if (active) {
      #pragma unroll
      for (int ks = 0; ks < K / 32; ++ks) {
        const int k0 = ks * 32 + q * 8;
        if (half == 0) {
          if (AF32) {
            const float* X = (const float*)Xv;
            float4 a0 = *(const float4*)(X + (size_t)arow * K + k0);
            float4 a1 = *(const float4*)(X + (size_t)arow * K + k0 + 4);
            af[ks] = (bf16x8){(short)f2bf(a0.x), (short)f2bf(a0.y),
                              (short)f2bf(a0.z), (short)f2bf(a0.w),
                              (short)f2bf(a1.x), (short)f2bf(a1.y),
                              (short)f2bf(a1.z), (short)f2bf(a1.w)};
          } else {
            af[ks] = *(const bf16x8*)((const unsigned short*)Xv +
                                      (size_t)arow * K + k0);
          }
        }
        #pragma unroll
        for (int ntl = 0; ntl < 4; ++ntl) {
          bf16x8 bf = *(const bf16x8*)(Bs + (ntl * 16 + m) * KP + k0);
          acc[half * 4 + ntl] =
              __builtin_amdgcn_mfma_f32_16x16x32_bf16(af[ks], bf, acc[half * 4 + ntl],
                                                      0, 0, 0);
        }
      }
    }
  }
  if (!active) return;
  #pragma unroll
  for (int r = 0; r < 4; ++r) {
    int grow = row0 + q * 4 + r;
    float di = dinv[grow];
    #pragma unroll
    for (int nt = 0; nt < 8; ++nt)
      hb[(size_t)grow * 128 + nt * 16 + m] = f2bf(acc[nt][r] * di);
  }
}

// ---------------- ELL gather-aggregate + bias + ReLU ----------------
// wave = 1 dst node; lane = uint (2 channels) of the 256B bf16 row; 16-deep
// unrolled edge loop -> 16 independent full-row gathers in flight.
template <bool BF16OUT>
__global__ __launch_bounds__(256) void k_agg(const unsigned int* __restrict__ hb,
                                             const int* __restrict__ cnt,
                                             const unsigned short* __restrict__ col,
                                             const float* __restrict__ dinv,
                                             const int* __restrict__ ovf_cnt,
                                             const int* __restrict__ ovf,
                                             const float* __restrict__ bias,
                                             void* __restrict__ outv, int n) {
  const int wave = threadIdx.x >> 6;
  const int lane = threadIdx.x & 63;
  const int d = blockIdx.x * 4 + wave;
  if (d >= n) return;

  // self-loop: hb pre-scaled by dinv, so hb[d]*dinv[d] = h[d]*dinv^2
  float2 acc = bfpair(hb[(size_t)d * 64 + lane]);

  int m = cnt[d]; if (m > ELL_STRIDE) m = ELL_STRIDE;
  const unsigned short* crow = col + (size_t)d * ELL_STRIDE;
  int k = 0;
  for (; k + 16 <= m; k += 16) {
    ushort4 c0 = *(const ushort4*)(crow + k);
    ushort4 c1 = *(const ushort4*)(crow + k + 4);
    ushort4 c2 = *(const ushort4*)(crow + k + 8);
    ushort4 c3 = *(const ushort4*)(crow + k + 12);
    unsigned int p0 = hb[(size_t)c0.x * 64 + lane];
    unsigned int p1 = hb[(size_t)c0.y * 64 + lane];
    unsigned int p2 = hb[(size_t)c0.z * 64 + lane];
    unsigned int p3 = hb[(size_t)c0.w * 64 + lane];
    unsigned int p4 = hb[(size_t)c1.x * 64 + lane];
    unsigned int p5 = hb[(size_t)c1.y * 64 + lane];
    unsigned int p6 = hb[(size_t)c1.z * 64 + lane];
    unsigned int p7 = hb[(size_t)c1.w * 64 + lane];
    unsigned int p8 = hb[(size_t)c2.x * 64 + lane];
    unsigned int p9 = hb[(size_t)c2.y * 64 + lane];
    unsigned int pa = hb[(size_t)c2.z * 64 + lane];
    unsigned int pb = hb[(size_t)c2.w * 64 + lane];
    unsigned int pc = hb[(size_t)c3.x * 64 + lane];
    unsigned int pd = hb[(size_t)c3.y * 64 + lane];
    unsigned int pe = hb[(size_t)c3.z * 64 + lane];
    unsigned int pf = hb[(size_t)c3.w * 64 + lane];
    float2 v0 = bfpair(p0), v1 = bfpair(p1), v2 = bfpair(p2), v3 = bfpair(p3);
    float2 v4 = bfpair(p4), v5 = bfpair(p5), v6 = bfpair(p6), v7 = bfpair(p7);
    acc.x += v0.x + v1.x + v2.x + v3.x + v4.x + v5.x + v6.x + v7.x;
    acc.y += v0.y + v1.y + v2.y + v3.y + v4.y + v5.y + v6.y + v7.y;
    float2 v8 = bfpair(p8), v9 = bfpair(p9), va = bfpair(pa), vb = bfpair(pb);
    float2 vc = bfpair(pc), vd = bfpair(pd), ve = bfpair(pe), vf = bfpair(pf);
    acc.x += v8.x + v9.x + va.x + vb.x + vc.x + vd.x + ve.x + vf.x;
    acc.y += v8.y + v9.y + va.y + vb.y + vc.y + vd.y + ve.y + vf.y;
  }
  for (; k + 8 <= m; k += 8) {
    ushort4 ca = *(const ushort4*)(crow + k);
    ushort4 cb = *(const ushort4*)(crow + k + 4);
    unsigned int p0 = hb[(size_t)ca.x * 64 + lane];
    unsigned int p1 = hb[(size_t)ca.y * 64 + lane];
    unsigned int p2 = hb[(size_t)ca.z * 64 + lane];
    unsigned int p3 = hb[(size_t)ca.w * 64 + lane];
    unsigned int p4 = hb[(size_t)cb.x * 64 + lane];
    unsigned int p5 = hb[(size_t)cb.y * 64 + lane];
    unsigned int p6 = hb[(size_t)cb.z * 64 + lane];
    unsigned int p7 = hb[(size_t)cb.w * 64 + lane];
    float2 v0 = bfpair(p0), v1 = bfpair(p1), v2 = bfpair(p2), v3 = bfpair(p3);
    float2 v4 = bfpair(p4), v5 = bfpair(p5), v6 = bfpair(p6), v7 = bfpair(p7);
    acc.x += v0.x + v1.x + v2.x + v3.x + v4.x + v5.x + v6.x + v7.x;
    acc.y += v0.y + v1.y + v2.y + v3.y + v4.y + v5.y + v6.y + v7.y;
  }
  for (; k < m; ++k) {
    int c = crow[k];
    float2 v = bfpair(hb[(size_t)c * 64 + lane]);
    acc.x += v.x; acc.y += v.y;
  }
  int V = *ovf_cnt; if (V > OVF_CAP) V = OVF_CAP;
  for (int j = 0; j < V; ++j) {
    if (ovf[2 * j + 1] == d) {
      float2 v = bfpair(hb[(size_t)ovf[2 * j] * 64 + lane]);
      acc.x += v.x; acc.y += v.y;
    }
  }
  float di = dinv[d];
  float2 bv = *(const float2*)(bias + lane * 2);
  float rx = di * acc.x + bv.x;
  float ry = di * acc.y + bv.y;
  rx = rx > 0.f ? rx : 0.f;
  ry = ry > 0.f ? ry : 0.f;
  if (BF16OUT) {
    unsigned int pk = (unsigned int)f2bf(rx) | ((unsigned int)f2bf(ry) << 16);
    ((unsigned int*)outv)[(size_t)d * 64 + lane] = pk;
  } else {
    *(float2*)((float*)outv + (size_t)d * 128 + lane * 2) = make_float2(rx, ry);
  }
}

// ---------------------------------------------------------------------------
extern "C" void kernel_launch(void* const* d_in, const int* in_sizes, int n_in,
                              void* d_out, int out_size, void* d_ws, size_t ws_size,
                              hipStream_t stream) {
  const float* x  = (const float*)d_in[0];
  const int*   ei = (const int*)d_in[1];
  const float* W1 = (const float*)d_in[2];
  const float* b1 = (const float*)d_in[3];
  const float* W2 = (const float*)d_in[4];
  const float* b2 = (const float*)d_in[5];
  float* out = (float*)d_out;

  const int IN_CH = 256;
  const int N = in_sizes[0] / IN_CH;   // 50000
  const int E = in_sizes[1] / 2;       // 1,600,000
  const int NB = (N + 127) >> 7;       // 391 buckets

  const int* src = ei;
  const int* dst = ei + E;

  char* ws = (char*)d_ws;
  size_t off = 0;
  auto carve = [&](size_t bytes) {
    void* p = ws + off;
    off += (bytes + 255) & ~(size_t)255;
    return p;
  };
  int*            cursor  = (int*)carve((size_t)NB * 4);
  int*            ovf_cnt = (int*)carve(4);
  int*            ovf     = (int*)carve((size_t)OVF_CAP * 2 * 4);
  int*            cnt     = (int*)carve((size_t)N * 4);
  float*          dinv    = (float*)carve((size_t)N * 4);
  unsigned short* col     = (unsigned short*)carve((size_t)N * ELL_STRIDE * 2); // 6.4MB
  unsigned short* hb      = (unsigned short*)carve((size_t)N * 128 * 2);        // 12.8MB
  unsigned short* WT1     = (unsigned short*)carve(128 * 256 * 2);
  unsigned short* WT2     = (unsigned short*)carve(128 * 128 * 2);
  // union: part (dead after k_fill2) aliases aggbuf (bf16, by k_agg#1)
  char*           unionp  = (char*)carve((size_t)NB * BCAP * 4);   // 12.8MB
  unsigned int*   part    = (unsigned int*)unionp;
  unsigned short* aggbuf  = (unsigned short*)unionp;               // [N][128] bf16

  k_cvt_w<<<(128 * 256 + 128 * 128 + 255) / 256, 256, 0, stream>>>(
      W1, W2, WT1, WT2, cursor, ovf_cnt, NB);
  k_part <<<(E + PART_T - 1) / PART_T, 256, 0, stream>>>(src, dst, cursor, part,
                                                         ovf_cnt, ovf, E, NB);
  k_fill2<<<NB, 256, 0, stream>>>(part, cursor, col, cnt, dinv, ovf_cnt, ovf, N);

  int gblocks = (N + 63) / 64;         // 782
  int ablocks = (N + 3) / 4;           // 12500
  k_gemm_mfma<256, true ><<<gblocks, 256, 0, stream>>>(x, WT1, dinv, hb, N);
  k_agg<true ><<<ablocks, 256, 0, stream>>>((const unsigned int*)hb, cnt, col, dinv,
                                            ovf_cnt, ovf, b1, aggbuf, N);
  k_gemm_mfma<128, false><<<gblocks, 256, 0, stream>>>(aggbuf, WT2, dinv, hb, N);
  k_agg<false><<<ablocks, 256, 0, stream>>>((const unsigned int*)hb, cnt, col, dinv,
                                            ovf_cnt, ovf, b2, out, N);
}